// Round 7
// baseline (623.169 us; speedup 1.0000x reference)
//
#include <hip/hip_runtime.h>
#include <hip/hip_fp16.h>
#include <math.h>

#define NN 51200
#define NE 2048000
#define F 128
#define NSEG 80
#define SEGSZ 25600   // NE / NSEG
#define NR 13         // ceil(NN / 4096)
#define RSZ 4096

typedef _Float16 half8 __attribute__((ext_vector_type(8)));
typedef float floatx4 __attribute__((ext_vector_type(4)));

__device__ __forceinline__ float mish_f(float x) {
  if (x > 20.0f) return x;
  float e = __expf(x);
  float w = 1.0f + e;
  w = w * w;
  return x * (w - 1.0f) / (w + 1.0f);
}

// ---- pass1: per-(segment, dst-range) LDS histogram: count + ew-sum -------
__global__ __launch_bounds__(256) void k_hist(const int* __restrict__ ei, const float* __restrict__ ew,
                                              unsigned* __restrict__ M, float* __restrict__ D) {
  __shared__ unsigned lc[RSZ];
  __shared__ float ld[RSZ];
  int s = blockIdx.x, r = blockIdx.y, t = threadIdx.x;
  int c0 = r * RSZ;
  int len = min(RSZ, NN - c0);
  for (int i = t; i < RSZ; i += 256) {
    lc[i] = 0u;
    ld[i] = 0.f;
  }
  __syncthreads();
  int base = s * SEGSZ;
  for (int it = 0; it < SEGSZ; it += 256) {
    int e = base + it + t;
    int c = ei[NE + e];
    unsigned lo = (unsigned)(c - c0);
    if (lo < (unsigned)RSZ) {
      atomicAdd(&lc[lo], 1u);
      atomicAdd(&ld[lo], ew[e]);
    }
  }
  __syncthreads();
  for (int i = t; i < len; i += 256) {
    M[(size_t)s * NN + c0 + i] = lc[i];
    D[(size_t)s * NN + c0 + i] = ld[i];
  }
}

// ---- pass2: per-dst prefix over segments; cnt + dinv ---------------------
__global__ __launch_bounds__(256) void k_seg(unsigned* __restrict__ M, const float* __restrict__ D,
                                             int* __restrict__ cnt, float* __restrict__ dinv) {
  int d = blockIdx.x * 256 + threadIdx.x;  // grid covers exactly NN
  unsigned run = 0;
  float ds = 0.f;
  for (int s = 0; s < NSEG; ++s) {
    size_t idx = (size_t)s * NN + d;
    unsigned m = M[idx];
    M[idx] = run;
    run += m;
    ds += D[idx];
  }
  cnt[d] = (int)run;
  dinv[d] = rsqrtf(ds + 1.0f);  // +1 = self-loop weight
}

// ---- hierarchical exclusive scan of cnt -> rowptr ------------------------
__global__ __launch_bounds__(256) void k_scan1(const int* __restrict__ cnt, int* __restrict__ bsum) {
  int i = blockIdx.x * 256 + threadIdx.x;
  int s = cnt[i];
#pragma unroll
  for (int off = 1; off < 64; off <<= 1) s += __shfl_xor(s, off);
  __shared__ int wsum[4];
  if ((threadIdx.x & 63) == 0) wsum[threadIdx.x >> 6] = s;
  __syncthreads();
  if (threadIdx.x == 0) bsum[blockIdx.x] = wsum[0] + wsum[1] + wsum[2] + wsum[3];
}

__global__ __launch_bounds__(256) void k_scan2(const int* __restrict__ bsum, int* __restrict__ boff,
                                               int* __restrict__ rowptr) {
  int t = threadIdx.x;
  int lane = t & 63, wid = t >> 6;
  int v = (t < 200) ? bsum[t] : 0;
  int x = v;
#pragma unroll
  for (int off = 1; off < 64; off <<= 1) {
    int y = __shfl_up(x, off);
    if (lane >= off) x += y;
  }
  __shared__ int ws4[4];
  if (lane == 63) ws4[wid] = x;
  __syncthreads();
  int woff = 0;
  for (int k = 0; k < wid; ++k) woff += ws4[k];
  if (t < 200) boff[t] = woff + x - v;
  if (t == 255) rowptr[NN] = woff + x;  // grand total
}

__global__ __launch_bounds__(256) void k_scan3(const int* __restrict__ cnt, const int* __restrict__ boff,
                                               int* __restrict__ rowptr) {
  int i = blockIdx.x * 256 + threadIdx.x;
  int t = threadIdx.x;
  int lane = t & 63, wid = t >> 6;
  int v = cnt[i];
  int x = v;
#pragma unroll
  for (int off = 1; off < 64; off <<= 1) {
    int y = __shfl_up(x, off);
    if (lane >= off) x += y;
  }
  __shared__ int ws4[4];
  if (lane == 63) ws4[wid] = x;
  __syncthreads();
  int woff = boff[blockIdx.x];
  for (int k = 0; k < wid; ++k) woff += ws4[k];
  rowptr[i] = woff + x - v;
}

// ---- pass3: scatter into CSR, LDS cursors, weight = dinv[src]*ew ---------
__global__ __launch_bounds__(256) void k_scatter(const int* __restrict__ ei, const float* __restrict__ ew,
                                                 const unsigned* __restrict__ M, const int* __restrict__ rowptr,
                                                 const float* __restrict__ dinv, int2* __restrict__ csr) {
  __shared__ int cur[RSZ];
  int s = blockIdx.x, r = blockIdx.y, t = threadIdx.x;
  int c0 = r * RSZ;
  int len = min(RSZ, NN - c0);
  for (int i = t; i < len; i += 256)
    cur[i] = rowptr[c0 + i] + (int)M[(size_t)s * NN + c0 + i];
  __syncthreads();
  int base = s * SEGSZ;
  for (int it = 0; it < SEGSZ; it += 256) {
    int e = base + it + t;
    int c = ei[NE + e];
    unsigned lo = (unsigned)(c - c0);
    if (lo < (unsigned)len) {
      int src = ei[e];
      float v = dinv[src] * ew[e];
      int p = atomicAdd(&cur[lo], 1);
      csr[p] = make_int2(src, __float_as_int(v));
    }
  }
}

// ---- W[K][128] fp32 -> Wt[128][K] fp16 -----------------------------------
__global__ void k_prep_w(const float* __restrict__ W, _Float16* __restrict__ Wt, int K) {
  int idx = blockIdx.x * blockDim.x + threadIdx.x;
  if (idx < K * 128) {
    int k = idx >> 7, n = idx & 127;
    Wt[n * K + k] = (_Float16)W[idx];
  }
}

// ---- MFMA GEMM: C[M,128](fp16) = A[M,K] @ W[K,128] -----------------------
template <bool A_IS_F32>
__global__ __launch_bounds__(256) void k_gemm16(const void* __restrict__ Av,
                                                const _Float16* __restrict__ Wt,
                                                __half* __restrict__ C, int K) {
  __shared__ _Float16 As[128][40];
  __shared__ _Float16 Bs[128][40];
  int t = threadIdx.x;
  int bm = blockIdx.x * 128;
  int w = t >> 6, l = t & 63, rr = l & 15, q = l >> 4;
  int si = t >> 1, sj = (t & 1) * 16;

  floatx4 acc[2][8];
#pragma unroll
  for (int a = 0; a < 2; ++a)
#pragma unroll
    for (int b = 0; b < 8; ++b) acc[a][b] = (floatx4){0.f, 0.f, 0.f, 0.f};

  for (int k0 = 0; k0 < K; k0 += 32) {
    if (A_IS_F32) {
      const float* A = (const float*)Av;
      half8 h0, h1;
      if (k0 + sj < K) {
        const float* ap = A + (size_t)(bm + si) * K + k0 + sj;
        float4 v0 = *(const float4*)(ap + 0);
        float4 v1 = *(const float4*)(ap + 4);
        float4 v2 = *(const float4*)(ap + 8);
        float4 v3 = *(const float4*)(ap + 12);
        h0 = (half8){(_Float16)v0.x, (_Float16)v0.y, (_Float16)v0.z, (_Float16)v0.w,
                     (_Float16)v1.x, (_Float16)v1.y, (_Float16)v1.z, (_Float16)v1.w};
        h1 = (half8){(_Float16)v2.x, (_Float16)v2.y, (_Float16)v2.z, (_Float16)v2.w,
                     (_Float16)v3.x, (_Float16)v3.y, (_Float16)v3.z, (_Float16)v3.w};
      } else {
        h0 = (half8){0, 0, 0, 0, 0, 0, 0, 0};
        h1 = h0;
      }
      *(half8*)&As[si][sj] = h0;
      *(half8*)&As[si][sj + 8] = h1;
    } else {
      const __half* A = (const __half*)Av;
      uint4 u0, u1;
      if (k0 + sj < K) {
        const __half* ap = A + (size_t)(bm + si) * K + k0 + sj;
        u0 = *(const uint4*)ap;
        u1 = *(const uint4*)(ap + 8);
      } else {
        u0 = make_uint4(0, 0, 0, 0);
        u1 = u0;
      }
      *(uint4*)&As[si][sj] = u0;
      *(uint4*)&As[si][sj + 8] = u1;
    }
    {
      uint4 u0, u1;
      if (k0 + sj < K) {
        const _Float16* wp = Wt + (size_t)si * K + k0 + sj;
        u0 = *(const uint4*)wp;
        u1 = *(const uint4*)(wp + 8);
      } else {
        u0 = make_uint4(0, 0, 0, 0);
        u1 = u0;
      }
      *(uint4*)&Bs[si][sj] = u0;
      *(uint4*)&Bs[si][sj + 8] = u1;
    }
    __syncthreads();

    half8 a0 = *(const half8*)&As[w * 32 + rr][q * 8];
    half8 a1 = *(const half8*)&As[w * 32 + 16 + rr][q * 8];
#pragma unroll
    for (int nt = 0; nt < 8; ++nt) {
      half8 b = *(const half8*)&Bs[nt * 16 + rr][q * 8];
      acc[0][nt] = __builtin_amdgcn_mfma_f32_16x16x32_f16(a0, b, acc[0][nt], 0, 0, 0);
      acc[1][nt] = __builtin_amdgcn_mfma_f32_16x16x32_f16(a1, b, acc[1][nt], 0, 0, 0);
    }
    __syncthreads();
  }
#pragma unroll
  for (int mt = 0; mt < 2; ++mt)
#pragma unroll
    for (int nt = 0; nt < 8; ++nt)
#pragma unroll
      for (int r4 = 0; r4 < 4; ++r4) {
        int row = bm + w * 32 + mt * 16 + q * 4 + r4;
        C[(size_t)row * 128 + nt * 16 + rr] = __float2half(acc[mt][nt][r4]);
      }
}

// ---- CSR aggregation + bias + mish: one node per WAVE, unroll 8 ----------
// csr weight = dinv[src]*ew; dst factor applied once: acc = di*(di*self + sum)
__global__ __launch_bounds__(256) void k_agg(const __half2* __restrict__ h, const int* __restrict__ rowptr,
                                             const int2* __restrict__ csr, const float* __restrict__ dinv,
                                             const float* __restrict__ bias, __half2* __restrict__ out) {
  int lane = threadIdx.x & 63;
  int n = blockIdx.x * 4 + (threadIdx.x >> 6);
  float di = dinv[n];
  float2 self = __half22float2(h[(size_t)n * 64 + lane]);
  float sx = 0.f, sy = 0.f;
  int p = rowptr[n], p1 = rowptr[n + 1];
  for (; p + 8 <= p1; p += 8) {
    int2 c[8];
#pragma unroll
    for (int u = 0; u < 8; ++u) c[u] = csr[p + u];
    float2 f[8];
#pragma unroll
    for (int u = 0; u < 8; ++u) f[u] = __half22float2(h[(size_t)c[u].x * 64 + lane]);
#pragma unroll
    for (int u = 0; u < 8; ++u) {
      float w = __int_as_float(c[u].y);
      sx += w * f[u].x;
      sy += w * f[u].y;
    }
  }
  for (; p < p1; ++p) {
    int2 c0 = csr[p];
    float2 f0 = __half22float2(h[(size_t)c0.x * 64 + lane]);
    float w = __int_as_float(c0.y);
    sx += w * f0.x;
    sy += w * f0.y;
  }
  float ax = di * (di * self.x + sx);
  float ay = di * (di * self.y + sy);
  float2 bb = ((const float2*)bias)[lane];
  out[(size_t)n * 64 + lane] = __floats2half2_rn(mish_f(ax + bb.x), mish_f(ay + bb.y));
}

// ---- readout (fp16 h): o8[n,k] = mish(h[n,:]@ro_w[:,k] + ro_b[k]) --------
__global__ __launch_bounds__(256) void k_ro(const __half2* __restrict__ h, const float* __restrict__ rw,
                                            const float* __restrict__ rb, float* __restrict__ o8) {
  __shared__ float w[128 * 8];
  int t = threadIdx.x;
  for (int i = t; i < 1024; i += 256) w[i] = rw[i];
  __syncthreads();
  int n = blockIdx.x * 32 + (t >> 3);
  int k = t & 7;
  const __half2* hr = h + (size_t)n * 64;
  float acc = rb[k];
#pragma unroll 4
  for (int j = 0; j < 64; ++j) {
    float2 hv = __half22float2(hr[j]);
    acc += hv.x * w[(2 * j) * 8 + k] + hv.y * w[(2 * j + 1) * 8 + k];
  }
  o8[(size_t)n * 8 + k] = mish_f(acc);
}

// ---- fc1 split-K: z += feats[g, kc:kc+128] @ w[kc:kc+128, :] -------------
__global__ void k_fc1_init(const float* __restrict__ b, float* __restrict__ z) {
  int i = blockIdx.x * blockDim.x + threadIdx.x;
  if (i < 128 * 400) z[i] = b[i % 400];
}

__global__ __launch_bounds__(448) void k_fc1(const float* __restrict__ feats, const float* __restrict__ w,
                                             float* __restrict__ z) {
  __shared__ float fs[8][128];
  int t = threadIdx.x;
  int kc = blockIdx.x * 128;
  int g0 = blockIdx.y * 8;
  for (int i = t; i < 1024; i += 448) {
    int g = i >> 7, k = i & 127;
    fs[g][k] = feats[(size_t)(g0 + g) * 3200 + kc + k];
  }
  __syncthreads();
  if (t < 400) {
    float a[8];
#pragma unroll
    for (int g = 0; g < 8; ++g) a[g] = 0.0f;
    for (int k = 0; k < 128; ++k) {
      float wv = w[(size_t)(kc + k) * 400 + t];
#pragma unroll
      for (int g = 0; g < 8; ++g) a[g] += fs[g][k] * wv;
    }
#pragma unroll
    for (int g = 0; g < 8; ++g) atomicAdd(&z[(size_t)(g0 + g) * 400 + t], a[g]);
  }
}

// ---- batchnorm stats: one block per feature, thread = batch element ------
__global__ __launch_bounds__(128) void k_bn(const float* __restrict__ z, const float* __restrict__ gamma,
                                            const float* __restrict__ beta, float* __restrict__ gs,
                                            float* __restrict__ gb) {
  int j = blockIdx.x;
  int b = threadIdx.x;
  float v = z[b * 400 + j];
  float s = v, s2 = v * v;
#pragma unroll
  for (int off = 1; off < 64; off <<= 1) {
    s += __shfl_xor(s, off);
    s2 += __shfl_xor(s2, off);
  }
  __shared__ float ls[2], ls2[2];
  if ((b & 63) == 0) {
    ls[b >> 6] = s;
    ls2[b >> 6] = s2;
  }
  __syncthreads();
  if (b == 0) {
    float mu = (ls[0] + ls[1]) * (1.0f / 128.0f);
    float var = (ls2[0] + ls2[1]) * (1.0f / 128.0f) - mu * mu;
    float rs = rsqrtf(var + 1e-5f);
    float g = gamma[j] * rs;
    gs[j] = g;
    gb[j] = beta[j] - mu * g;
  }
}

// ---- fc2: one block per graph, block-reduce over j -----------------------
__global__ __launch_bounds__(256) void k_fc2(const float* __restrict__ z, const float* __restrict__ gs,
                                             const float* __restrict__ gb, const float* __restrict__ w2,
                                             const float* __restrict__ b2, float* __restrict__ out) {
  int bg = blockIdx.x;
  int t = threadIdx.x;
  float a0 = 0.f, a1 = 0.f;
  for (int j = t; j < 400; j += 256) {
    float zn = z[bg * 400 + j] * gs[j] + gb[j];
    float m = mish_f(zn);
    a0 += m * w2[j * 2];
    a1 += m * w2[j * 2 + 1];
  }
#pragma unroll
  for (int off = 1; off < 64; off <<= 1) {
    a0 += __shfl_xor(a0, off);
    a1 += __shfl_xor(a1, off);
  }
  __shared__ float s0[4], s1[4];
  if ((t & 63) == 0) {
    s0[t >> 6] = a0;
    s1[t >> 6] = a1;
  }
  __syncthreads();
  if (t == 0) {
    out[bg * 2 + 0] = b2[0] + s0[0] + s0[1] + s0[2] + s0[3];
    out[bg * 2 + 1] = b2[1] + s1[0] + s1[1] + s1[2] + s1[3];
  }
}

extern "C" void kernel_launch(void* const* d_in, const int* in_sizes, int n_in,
                              void* d_out, int out_size, void* d_ws, size_t ws_size,
                              hipStream_t stream) {
  (void)in_sizes; (void)n_in; (void)out_size; (void)ws_size;
  const float* x   = (const float*)d_in[0];
  const int*   ei  = (const int*)d_in[1];
  const float* ew  = (const float*)d_in[2];
  const float* c1w = (const float*)d_in[4];
  const float* c1b = (const float*)d_in[5];
  const float* c2w = (const float*)d_in[6];
  const float* c2b = (const float*)d_in[7];
  const float* rw  = (const float*)d_in[8];
  const float* rb  = (const float*)d_in[9];
  const float* f1w = (const float*)d_in[10];
  const float* f1b = (const float*)d_in[11];
  const float* bng = (const float*)d_in[12];
  const float* bnb = (const float*)d_in[13];
  const float* f2w = (const float*)d_in[14];
  const float* f2b = (const float*)d_in[15];
  float* out = (float*)d_out;

  char* ws = (char*)d_ws;
  size_t off = 0;
  auto alloc = [&](size_t bytes) {
    void* p = ws + off;
    off = (off + bytes + 255) & ~(size_t)255;
    return p;
  };
  float* dinv   = (float*)alloc((size_t)NN * 4);
  int*   cnt    = (int*)alloc((size_t)NN * 4);
  int*   rowptr = (int*)alloc((size_t)(NN + 1) * 4);
  int*   bsum   = (int*)alloc(200 * 4);
  int*   boff   = (int*)alloc(200 * 4);
  unsigned* M   = (unsigned*)alloc((size_t)NSEG * NN * 4);  // 16.4 MB
  int2*  csr    = (int2*)alloc((size_t)NE * 8);             // 16.4 MB
  __half* A1    = (__half*)alloc((size_t)NN * F * 2);       // gemm out (fp16)
  __half* B1    = (__half*)alloc((size_t)NN * F * 2);       // agg out (fp16)
  _Float16* Wt1 = (_Float16*)alloc((size_t)400 * 128 * 2);
  _Float16* Wt2 = (_Float16*)alloc((size_t)128 * 128 * 2);
  float* o8     = (float*)alloc((size_t)NN * 8 * 4);
  float* z      = (float*)alloc((size_t)128 * 400 * 4);
  float* gs     = (float*)alloc(400 * 4);
  float* gb     = (float*)alloc(400 * 4);

  // D[s][d] (16.4 MB) aliases A1+B1 (26.2 MB): dead until gemm1 runs,
  // and D's last use (k_seg) completes before gemm1 on this stream.
  float* D = (float*)A1;

  {
    dim3 g(NSEG, NR);
    k_hist<<<g, 256, 0, stream>>>(ei, ew, M, D);
  }
  k_seg<<<NN / 256, 256, 0, stream>>>(M, D, cnt, dinv);
  k_scan1<<<NN / 256, 256, 0, stream>>>(cnt, bsum);
  k_scan2<<<1, 256, 0, stream>>>(bsum, boff, rowptr);
  k_scan3<<<NN / 256, 256, 0, stream>>>(cnt, boff, rowptr);
  {
    dim3 g(NSEG, NR);
    k_scatter<<<g, 256, 0, stream>>>(ei, ew, M, rowptr, dinv, csr);
  }

  k_prep_w<<<(400 * 128 + 255) / 256, 256, 0, stream>>>(c1w, Wt1, 400);
  k_prep_w<<<(128 * 128 + 255) / 256, 256, 0, stream>>>(c2w, Wt2, 128);

  // conv1: h = x@W1 (MFMA, fp16 out) ; agg+bias+mish (fp16 out)
  k_gemm16<true><<<NN / 128, 256, 0, stream>>>(x, Wt1, A1, 400);
  k_agg<<<NN / 4, 256, 0, stream>>>((const __half2*)A1, rowptr, csr, dinv, c1b, (__half2*)B1);
  // conv2
  k_gemm16<false><<<NN / 128, 256, 0, stream>>>(B1, Wt2, A1, 128);
  k_agg<<<NN / 4, 256, 0, stream>>>((const __half2*)A1, rowptr, csr, dinv, c2b, (__half2*)B1);
  // readout -> feats (o8 flat IS feats[128][3200])
  k_ro<<<NN / 32, 256, 0, stream>>>((const __half2*)B1, rw, rb, o8);
  k_fc1_init<<<(128 * 400 + 255) / 256, 256, 0, stream>>>(f1b, z);
  {
    dim3 g(25, 16);
    k_fc1<<<g, 448, 0, stream>>>(o8, f1w, z);
  }
  k_bn<<<400, 128, 0, stream>>>(z, bng, bnb, gs, gb);
  k_fc2<<<128, 256, 0, stream>>>(z, gs, gb, f2w, f2b, out);
}

// Round 8
// 459.244 us; speedup vs baseline: 1.3569x; 1.3569x over previous
//
#include <hip/hip_runtime.h>
#include <hip/hip_fp16.h>
#include <math.h>

#define NN 51200
#define NE 2048000
#define F 128
#define NB 1000        // coarse blocks
#define EPB 2048       // edges per coarse block (NB*EPB == NE)
#define NBKT 200       // coarse buckets (dst >> 8)

typedef _Float16 half8 __attribute__((ext_vector_type(8)));
typedef float floatx4 __attribute__((ext_vector_type(4)));

__device__ __forceinline__ float mish_f(float x) {
  if (x > 20.0f) return x;
  float e = __expf(x);
  float w = 1.0f + e;
  w = w * w;
  return x * (w - 1.0f) / (w + 1.0f);
}

// ---- pass A: coarse LDS histogram over dst>>8 ----------------------------
__global__ __launch_bounds__(256) void k_chist(const int* __restrict__ ei, unsigned* __restrict__ G) {
  __shared__ unsigned hist[NBKT];
  int blk = blockIdx.x, t = threadIdx.x;
  for (int i = t; i < NBKT; i += 256) hist[i] = 0u;
  __syncthreads();
  int base = blk * EPB;
  for (int it = 0; it < EPB; it += 256) {
    int dst = ei[NE + base + it + t];
    atomicAdd(&hist[dst >> 8], 1u);
  }
  __syncthreads();
  for (int i = t; i < NBKT; i += 256) G[(size_t)i * NB + blk] = hist[i];
}

// ---- pass B: per-bucket exclusive scan over the NB blocks (1 wave/bucket)
__global__ __launch_bounds__(64) void k_bscan(unsigned* __restrict__ G, unsigned* __restrict__ btot) {
  int b = blockIdx.x, l = threadIdx.x;
  unsigned base = (unsigned)l * 16;
  unsigned loc[16];
  unsigned s = 0;
#pragma unroll
  for (int i = 0; i < 16; ++i) {
    unsigned idx = base + i;
    unsigned x = (idx < NB) ? G[(size_t)b * NB + idx] : 0u;
    loc[i] = s;
    s += x;
  }
  unsigned run = s;
#pragma unroll
  for (int off = 1; off < 64; off <<= 1) {
    unsigned y = __shfl_up(run, off);
    if (l >= off) run += y;
  }
  unsigned excl = run - s;
#pragma unroll
  for (int i = 0; i < 16; ++i) {
    unsigned idx = base + i;
    if (idx < NB) G[(size_t)b * NB + idx] = excl + loc[i];
  }
  if (l == 63) btot[b] = run;
}

// ---- scan 200 bucket totals -> bbase[0..200] -----------------------------
__global__ __launch_bounds__(256) void k_bbase(const unsigned* __restrict__ btot, unsigned* __restrict__ bbase) {
  int t = threadIdx.x, lane = t & 63, wid = t >> 6;
  unsigned v = (t < NBKT) ? btot[t] : 0u;
  unsigned x = v;
#pragma unroll
  for (int off = 1; off < 64; off <<= 1) {
    unsigned y = __shfl_up(x, off);
    if (lane >= off) x += y;
  }
  __shared__ unsigned ws4[4];
  if (lane == 63) ws4[wid] = x;
  __syncthreads();
  unsigned woff = 0;
  for (int k = 0; k < wid; ++k) woff += ws4[k];
  if (t < NBKT) bbase[t] = woff + x - v;
  if (t == 255) bbase[NBKT] = woff + x;  // == NE
}

// ---- pass C: scatter edges into bucket-grouped E (packed src|dstLow, ew) -
__global__ __launch_bounds__(256) void k_cscat(const int* __restrict__ ei, const float* __restrict__ ew,
                                               const unsigned* __restrict__ G,
                                               const unsigned* __restrict__ bbase,
                                               uint2* __restrict__ E) {
  __shared__ unsigned cur[NBKT];
  int blk = blockIdx.x, t = threadIdx.x;
  for (int i = t; i < NBKT; i += 256) cur[i] = bbase[i] + G[(size_t)i * NB + blk];
  __syncthreads();
  int base = blk * EPB;
  for (int it = 0; it < EPB; it += 256) {
    int e = base + it + t;
    int dst = ei[NE + e];
    int src = ei[e];
    float w = ew[e];
    unsigned pos = atomicAdd(&cur[dst >> 8], 1u);
    E[pos] = make_uint2((unsigned)src | ((unsigned)(dst & 255) << 16), __float_as_uint(w));
  }
}

// ---- pass D1: per-bucket fine count + degree sum -> cnt, dinv ------------
__global__ __launch_bounds__(256) void k_fcnt(const uint2* __restrict__ E, const unsigned* __restrict__ bbase,
                                              int* __restrict__ cnt, float* __restrict__ dinv) {
  __shared__ unsigned lc[256];
  __shared__ float ld[256];
  int b = blockIdx.x, t = threadIdx.x;
  lc[t] = 0u;
  ld[t] = 0.f;
  __syncthreads();
  unsigned e0 = bbase[b], e1 = bbase[b + 1];
  for (unsigned e = e0 + t; e < e1; e += 256) {
    uint2 v = E[e];
    unsigned node = (v.x >> 16) & 255u;
    atomicAdd(&lc[node], 1u);
    atomicAdd(&ld[node], __uint_as_float(v.y));
  }
  __syncthreads();
  cnt[b * 256 + t] = (int)lc[t];
  dinv[b * 256 + t] = rsqrtf(ld[t] + 1.0f);  // +1 = self-loop weight
}

// ---- hierarchical exclusive scan of cnt -> rowptr ------------------------
__global__ __launch_bounds__(256) void k_scan1(const int* __restrict__ cnt, int* __restrict__ bsum) {
  int i = blockIdx.x * 256 + threadIdx.x;
  int s = cnt[i];
#pragma unroll
  for (int off = 1; off < 64; off <<= 1) s += __shfl_xor(s, off);
  __shared__ int wsum[4];
  if ((threadIdx.x & 63) == 0) wsum[threadIdx.x >> 6] = s;
  __syncthreads();
  if (threadIdx.x == 0) bsum[blockIdx.x] = wsum[0] + wsum[1] + wsum[2] + wsum[3];
}

__global__ __launch_bounds__(256) void k_scan2(const int* __restrict__ bsum, int* __restrict__ boff,
                                               int* __restrict__ rowptr) {
  int t = threadIdx.x;
  int lane = t & 63, wid = t >> 6;
  int v = (t < 200) ? bsum[t] : 0;
  int x = v;
#pragma unroll
  for (int off = 1; off < 64; off <<= 1) {
    int y = __shfl_up(x, off);
    if (lane >= off) x += y;
  }
  __shared__ int ws4[4];
  if (lane == 63) ws4[wid] = x;
  __syncthreads();
  int woff = 0;
  for (int k = 0; k < wid; ++k) woff += ws4[k];
  if (t < 200) boff[t] = woff + x - v;
  if (t == 255) rowptr[NN] = woff + x;  // grand total
}

__global__ __launch_bounds__(256) void k_scan3(const int* __restrict__ cnt, const int* __restrict__ boff,
                                               int* __restrict__ rowptr) {
  int i = blockIdx.x * 256 + threadIdx.x;
  int t = threadIdx.x;
  int lane = t & 63, wid = t >> 6;
  int v = cnt[i];
  int x = v;
#pragma unroll
  for (int off = 1; off < 64; off <<= 1) {
    int y = __shfl_up(x, off);
    if (lane >= off) x += y;
  }
  __shared__ int ws4[4];
  if (lane == 63) ws4[wid] = x;
  __syncthreads();
  int woff = boff[blockIdx.x];
  for (int k = 0; k < wid; ++k) woff += ws4[k];
  rowptr[i] = woff + x - v;
}

// ---- pass D2: per-bucket scatter into final CSR, w = dinv[src]*ew --------
__global__ __launch_bounds__(256) void k_fscat(const uint2* __restrict__ E, const unsigned* __restrict__ bbase,
                                               const int* __restrict__ rowptr, const float* __restrict__ dinv,
                                               int2* __restrict__ csr) {
  __shared__ int cur[256];
  int b = blockIdx.x, t = threadIdx.x;
  cur[t] = rowptr[b * 256 + t];
  __syncthreads();
  unsigned e0 = bbase[b], e1 = bbase[b + 1];
  for (unsigned e = e0 + t; e < e1; e += 256) {
    uint2 v = E[e];
    unsigned node = (v.x >> 16) & 255u;
    int src = (int)(v.x & 0xFFFFu);
    float w = dinv[src] * __uint_as_float(v.y);
    int p = atomicAdd(&cur[node], 1);
    csr[p] = make_int2(src, __float_as_int(w));
  }
}

// ---- W[K][128] fp32 -> Wt[128][K] fp16 -----------------------------------
__global__ void k_prep_w(const float* __restrict__ W, _Float16* __restrict__ Wt, int K) {
  int idx = blockIdx.x * blockDim.x + threadIdx.x;
  if (idx < K * 128) {
    int k = idx >> 7, n = idx & 127;
    Wt[n * K + k] = (_Float16)W[idx];
  }
}

// ---- MFMA GEMM: C[M,128](fp16) = A[M,K] @ W[K,128] -----------------------
template <bool A_IS_F32>
__global__ __launch_bounds__(256) void k_gemm16(const void* __restrict__ Av,
                                                const _Float16* __restrict__ Wt,
                                                __half* __restrict__ C, int K) {
  __shared__ _Float16 As[128][40];
  __shared__ _Float16 Bs[128][40];
  int t = threadIdx.x;
  int bm = blockIdx.x * 128;
  int w = t >> 6, l = t & 63, rr = l & 15, q = l >> 4;
  int si = t >> 1, sj = (t & 1) * 16;

  floatx4 acc[2][8];
#pragma unroll
  for (int a = 0; a < 2; ++a)
#pragma unroll
    for (int b = 0; b < 8; ++b) acc[a][b] = (floatx4){0.f, 0.f, 0.f, 0.f};

  for (int k0 = 0; k0 < K; k0 += 32) {
    if (A_IS_F32) {
      const float* A = (const float*)Av;
      half8 h0, h1;
      if (k0 + sj < K) {
        const float* ap = A + (size_t)(bm + si) * K + k0 + sj;
        float4 v0 = *(const float4*)(ap + 0);
        float4 v1 = *(const float4*)(ap + 4);
        float4 v2 = *(const float4*)(ap + 8);
        float4 v3 = *(const float4*)(ap + 12);
        h0 = (half8){(_Float16)v0.x, (_Float16)v0.y, (_Float16)v0.z, (_Float16)v0.w,
                     (_Float16)v1.x, (_Float16)v1.y, (_Float16)v1.z, (_Float16)v1.w};
        h1 = (half8){(_Float16)v2.x, (_Float16)v2.y, (_Float16)v2.z, (_Float16)v2.w,
                     (_Float16)v3.x, (_Float16)v3.y, (_Float16)v3.z, (_Float16)v3.w};
      } else {
        h0 = (half8){0, 0, 0, 0, 0, 0, 0, 0};
        h1 = h0;
      }
      *(half8*)&As[si][sj] = h0;
      *(half8*)&As[si][sj + 8] = h1;
    } else {
      const __half* A = (const __half*)Av;
      uint4 u0, u1;
      if (k0 + sj < K) {
        const __half* ap = A + (size_t)(bm + si) * K + k0 + sj;
        u0 = *(const uint4*)ap;
        u1 = *(const uint4*)(ap + 8);
      } else {
        u0 = make_uint4(0, 0, 0, 0);
        u1 = u0;
      }
      *(uint4*)&As[si][sj] = u0;
      *(uint4*)&As[si][sj + 8] = u1;
    }
    {
      uint4 u0, u1;
      if (k0 + sj < K) {
        const _Float16* wp = Wt + (size_t)si * K + k0 + sj;
        u0 = *(const uint4*)wp;
        u1 = *(const uint4*)(wp + 8);
      } else {
        u0 = make_uint4(0, 0, 0, 0);
        u1 = u0;
      }
      *(uint4*)&Bs[si][sj] = u0;
      *(uint4*)&Bs[si][sj + 8] = u1;
    }
    __syncthreads();

    half8 a0 = *(const half8*)&As[w * 32 + rr][q * 8];
    half8 a1 = *(const half8*)&As[w * 32 + 16 + rr][q * 8];
#pragma unroll
    for (int nt = 0; nt < 8; ++nt) {
      half8 b = *(const half8*)&Bs[nt * 16 + rr][q * 8];
      acc[0][nt] = __builtin_amdgcn_mfma_f32_16x16x32_f16(a0, b, acc[0][nt], 0, 0, 0);
      acc[1][nt] = __builtin_amdgcn_mfma_f32_16x16x32_f16(a1, b, acc[1][nt], 0, 0, 0);
    }
    __syncthreads();
  }
#pragma unroll
  for (int mt = 0; mt < 2; ++mt)
#pragma unroll
    for (int nt = 0; nt < 8; ++nt)
#pragma unroll
      for (int r4 = 0; r4 < 4; ++r4) {
        int row = bm + w * 32 + mt * 16 + q * 4 + r4;
        C[(size_t)row * 128 + nt * 16 + rr] = __float2half(acc[mt][nt][r4]);
      }
}

// ---- CSR aggregation + bias + mish: one node per WAVE, unroll 8 ----------
// csr weight = dinv[src]*ew; dst factor applied once: acc = di*(di*self + sum)
__global__ __launch_bounds__(256) void k_agg(const __half2* __restrict__ h, const int* __restrict__ rowptr,
                                             const int2* __restrict__ csr, const float* __restrict__ dinv,
                                             const float* __restrict__ bias, __half2* __restrict__ out) {
  int lane = threadIdx.x & 63;
  int n = blockIdx.x * 4 + (threadIdx.x >> 6);
  float di = dinv[n];
  float2 self = __half22float2(h[(size_t)n * 64 + lane]);
  float sx = 0.f, sy = 0.f;
  int p = rowptr[n], p1 = rowptr[n + 1];
  for (; p + 8 <= p1; p += 8) {
    int2 c[8];
#pragma unroll
    for (int u = 0; u < 8; ++u) c[u] = csr[p + u];
    float2 f[8];
#pragma unroll
    for (int u = 0; u < 8; ++u) f[u] = __half22float2(h[(size_t)c[u].x * 64 + lane]);
#pragma unroll
    for (int u = 0; u < 8; ++u) {
      float w = __int_as_float(c[u].y);
      sx += w * f[u].x;
      sy += w * f[u].y;
    }
  }
  for (; p < p1; ++p) {
    int2 c0 = csr[p];
    float2 f0 = __half22float2(h[(size_t)c0.x * 64 + lane]);
    float w = __int_as_float(c0.y);
    sx += w * f0.x;
    sy += w * f0.y;
  }
  float ax = di * (di * self.x + sx);
  float ay = di * (di * self.y + sy);
  float2 bb = ((const float2*)bias)[lane];
  out[(size_t)n * 64 + lane] = __floats2half2_rn(mish_f(ax + bb.x), mish_f(ay + bb.y));
}

// ---- readout (fp16 h): o8[n,k] = mish(h[n,:]@ro_w[:,k] + ro_b[k]) --------
__global__ __launch_bounds__(256) void k_ro(const __half2* __restrict__ h, const float* __restrict__ rw,
                                            const float* __restrict__ rb, float* __restrict__ o8) {
  __shared__ float w[128 * 8];
  int t = threadIdx.x;
  for (int i = t; i < 1024; i += 256) w[i] = rw[i];
  __syncthreads();
  int n = blockIdx.x * 32 + (t >> 3);
  int k = t & 7;
  const __half2* hr = h + (size_t)n * 64;
  float acc = rb[k];
#pragma unroll 4
  for (int j = 0; j < 64; ++j) {
    float2 hv = __half22float2(hr[j]);
    acc += hv.x * w[(2 * j) * 8 + k] + hv.y * w[(2 * j + 1) * 8 + k];
  }
  o8[(size_t)n * 8 + k] = mish_f(acc);
}

// ---- fc1 split-K: z += feats[g, kc:kc+128] @ w[kc:kc+128, :] -------------
__global__ void k_fc1_init(const float* __restrict__ b, float* __restrict__ z) {
  int i = blockIdx.x * blockDim.x + threadIdx.x;
  if (i < 128 * 400) z[i] = b[i % 400];
}

__global__ __launch_bounds__(448) void k_fc1(const float* __restrict__ feats, const float* __restrict__ w,
                                             float* __restrict__ z) {
  __shared__ float fs[8][128];
  int t = threadIdx.x;
  int kc = blockIdx.x * 128;
  int g0 = blockIdx.y * 8;
  for (int i = t; i < 1024; i += 448) {
    int g = i >> 7, k = i & 127;
    fs[g][k] = feats[(size_t)(g0 + g) * 3200 + kc + k];
  }
  __syncthreads();
  if (t < 400) {
    float a[8];
#pragma unroll
    for (int g = 0; g < 8; ++g) a[g] = 0.0f;
    for (int k = 0; k < 128; ++k) {
      float wv = w[(size_t)(kc + k) * 400 + t];
#pragma unroll
      for (int g = 0; g < 8; ++g) a[g] += fs[g][k] * wv;
    }
#pragma unroll
    for (int g = 0; g < 8; ++g) atomicAdd(&z[(size_t)(g0 + g) * 400 + t], a[g]);
  }
}

// ---- batchnorm stats: one block per feature, thread = batch element ------
__global__ __launch_bounds__(128) void k_bn(const float* __restrict__ z, const float* __restrict__ gamma,
                                            const float* __restrict__ beta, float* __restrict__ gs,
                                            float* __restrict__ gb) {
  int j = blockIdx.x;
  int b = threadIdx.x;
  float v = z[b * 400 + j];
  float s = v, s2 = v * v;
#pragma unroll
  for (int off = 1; off < 64; off <<= 1) {
    s += __shfl_xor(s, off);
    s2 += __shfl_xor(s2, off);
  }
  __shared__ float ls[2], ls2[2];
  if ((b & 63) == 0) {
    ls[b >> 6] = s;
    ls2[b >> 6] = s2;
  }
  __syncthreads();
  if (b == 0) {
    float mu = (ls[0] + ls[1]) * (1.0f / 128.0f);
    float var = (ls2[0] + ls2[1]) * (1.0f / 128.0f) - mu * mu;
    float rs = rsqrtf(var + 1e-5f);
    float g = gamma[j] * rs;
    gs[j] = g;
    gb[j] = beta[j] - mu * g;
  }
}

// ---- fc2: one block per graph, block-reduce over j -----------------------
__global__ __launch_bounds__(256) void k_fc2(const float* __restrict__ z, const float* __restrict__ gs,
                                             const float* __restrict__ gb, const float* __restrict__ w2,
                                             const float* __restrict__ b2, float* __restrict__ out) {
  int bg = blockIdx.x;
  int t = threadIdx.x;
  float a0 = 0.f, a1 = 0.f;
  for (int j = t; j < 400; j += 256) {
    float zn = z[bg * 400 + j] * gs[j] + gb[j];
    float m = mish_f(zn);
    a0 += m * w2[j * 2];
    a1 += m * w2[j * 2 + 1];
  }
#pragma unroll
  for (int off = 1; off < 64; off <<= 1) {
    a0 += __shfl_xor(a0, off);
    a1 += __shfl_xor(a1, off);
  }
  __shared__ float s0[4], s1[4];
  if ((t & 63) == 0) {
    s0[t >> 6] = a0;
    s1[t >> 6] = a1;
  }
  __syncthreads();
  if (t == 0) {
    out[bg * 2 + 0] = b2[0] + s0[0] + s0[1] + s0[2] + s0[3];
    out[bg * 2 + 1] = b2[1] + s1[0] + s1[1] + s1[2] + s1[3];
  }
}

extern "C" void kernel_launch(void* const* d_in, const int* in_sizes, int n_in,
                              void* d_out, int out_size, void* d_ws, size_t ws_size,
                              hipStream_t stream) {
  (void)in_sizes; (void)n_in; (void)out_size; (void)ws_size;
  const float* x   = (const float*)d_in[0];
  const int*   ei  = (const int*)d_in[1];
  const float* ew  = (const float*)d_in[2];
  const float* c1w = (const float*)d_in[4];
  const float* c1b = (const float*)d_in[5];
  const float* c2w = (const float*)d_in[6];
  const float* c2b = (const float*)d_in[7];
  const float* rw  = (const float*)d_in[8];
  const float* rb  = (const float*)d_in[9];
  const float* f1w = (const float*)d_in[10];
  const float* f1b = (const float*)d_in[11];
  const float* bng = (const float*)d_in[12];
  const float* bnb = (const float*)d_in[13];
  const float* f2w = (const float*)d_in[14];
  const float* f2b = (const float*)d_in[15];
  float* out = (float*)d_out;

  char* ws = (char*)d_ws;
  size_t off = 0;
  auto alloc = [&](size_t bytes) {
    void* p = ws + off;
    off = (off + bytes + 255) & ~(size_t)255;
    return p;
  };
  float* dinv    = (float*)alloc((size_t)NN * 4);
  int*   cnt     = (int*)alloc((size_t)NN * 4);
  int*   rowptr  = (int*)alloc((size_t)(NN + 1) * 4);
  int*   bsum    = (int*)alloc(200 * 4);
  int*   boff    = (int*)alloc(200 * 4);
  unsigned* G    = (unsigned*)alloc((size_t)NBKT * NB * 4);  // 800 KB
  unsigned* btot = (unsigned*)alloc(NBKT * 4);
  unsigned* bbase= (unsigned*)alloc((NBKT + 1) * 4);
  int2*  csr     = (int2*)alloc((size_t)NE * 8);             // 16.4 MB
  __half* A1     = (__half*)alloc((size_t)NN * F * 2);       // gemm out (fp16)
  __half* B1     = (__half*)alloc((size_t)NN * F * 2);       // agg out (fp16)
  _Float16* Wt1  = (_Float16*)alloc((size_t)400 * 128 * 2);
  _Float16* Wt2  = (_Float16*)alloc((size_t)128 * 128 * 2);
  float* o8      = (float*)alloc((size_t)NN * 8 * 4);
  float* z       = (float*)alloc((size_t)128 * 400 * 4);
  float* gs      = (float*)alloc(400 * 4);
  float* gb      = (float*)alloc(400 * 4);

  // E (16 MB) aliases A1+B1 (26 MB): E's last reader (k_fscat) completes
  // before gemm1 writes A1 (stream-ordered).
  uint2* E = (uint2*)A1;

  k_chist<<<NB, 256, 0, stream>>>(ei, G);
  k_bscan<<<NBKT, 64, 0, stream>>>(G, btot);
  k_bbase<<<1, 256, 0, stream>>>(btot, bbase);
  k_cscat<<<NB, 256, 0, stream>>>(ei, ew, G, bbase, E);
  k_fcnt<<<NBKT, 256, 0, stream>>>(E, bbase, cnt, dinv);
  k_scan1<<<NN / 256, 256, 0, stream>>>(cnt, bsum);
  k_scan2<<<1, 256, 0, stream>>>(bsum, boff, rowptr);
  k_scan3<<<NN / 256, 256, 0, stream>>>(cnt, boff, rowptr);
  k_fscat<<<NBKT, 256, 0, stream>>>(E, bbase, rowptr, dinv, csr);

  k_prep_w<<<(400 * 128 + 255) / 256, 256, 0, stream>>>(c1w, Wt1, 400);
  k_prep_w<<<(128 * 128 + 255) / 256, 256, 0, stream>>>(c2w, Wt2, 128);

  // conv1: h = x@W1 (MFMA, fp16 out) ; agg+bias+mish (fp16 out)
  k_gemm16<true><<<NN / 128, 256, 0, stream>>>(x, Wt1, A1, 400);
  k_agg<<<NN / 4, 256, 0, stream>>>((const __half2*)A1, rowptr, csr, dinv, c1b, (__half2*)B1);
  // conv2
  k_gemm16<false><<<NN / 128, 256, 0, stream>>>(B1, Wt2, A1, 128);
  k_agg<<<NN / 4, 256, 0, stream>>>((const __half2*)A1, rowptr, csr, dinv, c2b, (__half2*)B1);
  // readout -> feats (o8 flat IS feats[128][3200])
  k_ro<<<NN / 32, 256, 0, stream>>>((const __half2*)B1, rw, rb, o8);
  k_fc1_init<<<(128 * 400 + 255) / 256, 256, 0, stream>>>(f1b, z);
  {
    dim3 g(25, 16);
    k_fc1<<<g, 448, 0, stream>>>(o8, f1w, z);
  }
  k_bn<<<400, 128, 0, stream>>>(z, bng, bnb, gs, gb);
  k_fc2<<<128, 256, 0, stream>>>(z, gs, gb, f2w, f2b, out);
}

// Round 9
// 436.793 us; speedup vs baseline: 1.4267x; 1.0514x over previous
//
#include <hip/hip_runtime.h>
#include <hip/hip_fp16.h>
#include <math.h>

#define NN 51200
#define NE 2048000
#define F 128
#define NB 1000        // coarse blocks
#define EPB 2048       // edges per coarse block (NB*EPB == NE)
#define NBKT 200       // coarse buckets (dst >> 8)

typedef _Float16 half8 __attribute__((ext_vector_type(8)));
typedef float floatx4 __attribute__((ext_vector_type(4)));

__device__ __forceinline__ float mish_f(float x) {
  if (x > 20.0f) return x;
  float e = __expf(x);
  float w = 1.0f + e;
  w = w * w;
  return x * (w - 1.0f) / (w + 1.0f);
}

// ---- pass A: coarse LDS histogram over dst>>8 ----------------------------
__global__ __launch_bounds__(256) void k_chist(const int* __restrict__ ei, unsigned* __restrict__ G) {
  __shared__ unsigned hist[NBKT];
  int blk = blockIdx.x, t = threadIdx.x;
  for (int i = t; i < NBKT; i += 256) hist[i] = 0u;
  __syncthreads();
  int base = blk * EPB;
  for (int it = 0; it < EPB; it += 256) {
    int dst = ei[NE + base + it + t];
    atomicAdd(&hist[dst >> 8], 1u);
  }
  __syncthreads();
  for (int i = t; i < NBKT; i += 256) G[(size_t)i * NB + blk] = hist[i];
}

// ---- pass B: per-bucket exclusive scan over the NB blocks (1 wave/bucket)
__global__ __launch_bounds__(64) void k_bscan(unsigned* __restrict__ G, unsigned* __restrict__ btot) {
  int b = blockIdx.x, l = threadIdx.x;
  unsigned base = (unsigned)l * 16;
  unsigned loc[16];
  unsigned s = 0;
#pragma unroll
  for (int i = 0; i < 16; ++i) {
    unsigned idx = base + i;
    unsigned x = (idx < NB) ? G[(size_t)b * NB + idx] : 0u;
    loc[i] = s;
    s += x;
  }
  unsigned run = s;
#pragma unroll
  for (int off = 1; off < 64; off <<= 1) {
    unsigned y = __shfl_up(run, off);
    if (l >= off) run += y;
  }
  unsigned excl = run - s;
#pragma unroll
  for (int i = 0; i < 16; ++i) {
    unsigned idx = base + i;
    if (idx < NB) G[(size_t)b * NB + idx] = excl + loc[i];
  }
  if (l == 63) btot[b] = run;
}

// ---- scan 200 bucket totals -> bbase[0..200] -----------------------------
__global__ __launch_bounds__(256) void k_bbase(const unsigned* __restrict__ btot, unsigned* __restrict__ bbase) {
  int t = threadIdx.x, lane = t & 63, wid = t >> 6;
  unsigned v = (t < NBKT) ? btot[t] : 0u;
  unsigned x = v;
#pragma unroll
  for (int off = 1; off < 64; off <<= 1) {
    unsigned y = __shfl_up(x, off);
    if (lane >= off) x += y;
  }
  __shared__ unsigned ws4[4];
  if (lane == 63) ws4[wid] = x;
  __syncthreads();
  unsigned woff = 0;
  for (int k = 0; k < wid; ++k) woff += ws4[k];
  if (t < NBKT) bbase[t] = woff + x - v;
  if (t == 255) bbase[NBKT] = woff + x;  // == NE
}

// ---- pass C: scatter edges into bucket-grouped E (packed src|dstLow, ew) -
__global__ __launch_bounds__(256) void k_cscat(const int* __restrict__ ei, const float* __restrict__ ew,
                                               const unsigned* __restrict__ G,
                                               const unsigned* __restrict__ bbase,
                                               uint2* __restrict__ E) {
  __shared__ unsigned cur[NBKT];
  int blk = blockIdx.x, t = threadIdx.x;
  for (int i = t; i < NBKT; i += 256) cur[i] = bbase[i] + G[(size_t)i * NB + blk];
  __syncthreads();
  int base = blk * EPB;
  for (int it = 0; it < EPB; it += 256) {
    int e = base + it + t;
    int dst = ei[NE + e];
    int src = ei[e];
    float w = ew[e];
    unsigned pos = atomicAdd(&cur[dst >> 8], 1u);
    E[pos] = make_uint2((unsigned)src | ((unsigned)(dst & 255) << 16), __float_as_uint(w));
  }
}

// ---- pass D1: per-bucket fine count + degree sum -> cnt, dinv ------------
__global__ __launch_bounds__(256) void k_fcnt(const uint2* __restrict__ E, const unsigned* __restrict__ bbase,
                                              int* __restrict__ cnt, float* __restrict__ dinv) {
  __shared__ unsigned lc[256];
  __shared__ float ld[256];
  int b = blockIdx.x, t = threadIdx.x;
  lc[t] = 0u;
  ld[t] = 0.f;
  __syncthreads();
  unsigned e0 = bbase[b], e1 = bbase[b + 1];
  for (unsigned e = e0 + t; e < e1; e += 256) {
    uint2 v = E[e];
    unsigned node = (v.x >> 16) & 255u;
    atomicAdd(&lc[node], 1u);
    atomicAdd(&ld[node], __uint_as_float(v.y));
  }
  __syncthreads();
  cnt[b * 256 + t] = (int)lc[t];
  dinv[b * 256 + t] = rsqrtf(ld[t] + 1.0f);  // +1 = self-loop weight
}

// ---- hierarchical exclusive scan of cnt -> rowptr ------------------------
__global__ __launch_bounds__(256) void k_scan1(const int* __restrict__ cnt, int* __restrict__ bsum) {
  int i = blockIdx.x * 256 + threadIdx.x;
  int s = cnt[i];
#pragma unroll
  for (int off = 1; off < 64; off <<= 1) s += __shfl_xor(s, off);
  __shared__ int wsum[4];
  if ((threadIdx.x & 63) == 0) wsum[threadIdx.x >> 6] = s;
  __syncthreads();
  if (threadIdx.x == 0) bsum[blockIdx.x] = wsum[0] + wsum[1] + wsum[2] + wsum[3];
}

__global__ __launch_bounds__(256) void k_scan2(const int* __restrict__ bsum, int* __restrict__ boff,
                                               int* __restrict__ rowptr) {
  int t = threadIdx.x;
  int lane = t & 63, wid = t >> 6;
  int v = (t < 200) ? bsum[t] : 0;
  int x = v;
#pragma unroll
  for (int off = 1; off < 64; off <<= 1) {
    int y = __shfl_up(x, off);
    if (lane >= off) x += y;
  }
  __shared__ int ws4[4];
  if (lane == 63) ws4[wid] = x;
  __syncthreads();
  int woff = 0;
  for (int k = 0; k < wid; ++k) woff += ws4[k];
  if (t < 200) boff[t] = woff + x - v;
  if (t == 255) rowptr[NN] = woff + x;  // grand total
}

__global__ __launch_bounds__(256) void k_scan3(const int* __restrict__ cnt, const int* __restrict__ boff,
                                               int* __restrict__ rowptr) {
  int i = blockIdx.x * 256 + threadIdx.x;
  int t = threadIdx.x;
  int lane = t & 63, wid = t >> 6;
  int v = cnt[i];
  int x = v;
#pragma unroll
  for (int off = 1; off < 64; off <<= 1) {
    int y = __shfl_up(x, off);
    if (lane >= off) x += y;
  }
  __shared__ int ws4[4];
  if (lane == 63) ws4[wid] = x;
  __syncthreads();
  int woff = boff[blockIdx.x];
  for (int k = 0; k < wid; ++k) woff += ws4[k];
  rowptr[i] = woff + x - v;
}

// ---- pass D2: per-bucket scatter into final CSR, w = dinv[src]*ew --------
__global__ __launch_bounds__(256) void k_fscat(const uint2* __restrict__ E, const unsigned* __restrict__ bbase,
                                               const int* __restrict__ rowptr, const float* __restrict__ dinv,
                                               int2* __restrict__ csr) {
  __shared__ int cur[256];
  int b = blockIdx.x, t = threadIdx.x;
  cur[t] = rowptr[b * 256 + t];
  __syncthreads();
  unsigned e0 = bbase[b], e1 = bbase[b + 1];
  for (unsigned e = e0 + t; e < e1; e += 256) {
    uint2 v = E[e];
    unsigned node = (v.x >> 16) & 255u;
    int src = (int)(v.x & 0xFFFFu);
    float w = dinv[src] * __uint_as_float(v.y);
    int p = atomicAdd(&cur[node], 1);
    csr[p] = make_int2(src, __float_as_int(w));
  }
}

// ---- W[K][128] fp32 -> Wt[128][K] fp16 -----------------------------------
__global__ void k_prep_w(const float* __restrict__ W, _Float16* __restrict__ Wt, int K) {
  int idx = blockIdx.x * blockDim.x + threadIdx.x;
  if (idx < K * 128) {
    int k = idx >> 7, n = idx & 127;
    Wt[n * K + k] = (_Float16)W[idx];
  }
}

// ---- MFMA GEMM: C[M,128](fp16) = A[M,K] @ W[K,128] -----------------------
template <bool A_IS_F32>
__global__ __launch_bounds__(256) void k_gemm16(const void* __restrict__ Av,
                                                const _Float16* __restrict__ Wt,
                                                __half* __restrict__ C, int K) {
  __shared__ _Float16 As[128][40];
  __shared__ _Float16 Bs[128][40];
  int t = threadIdx.x;
  int bm = blockIdx.x * 128;
  int w = t >> 6, l = t & 63, rr = l & 15, q = l >> 4;
  int si = t >> 1, sj = (t & 1) * 16;

  floatx4 acc[2][8];
#pragma unroll
  for (int a = 0; a < 2; ++a)
#pragma unroll
    for (int b = 0; b < 8; ++b) acc[a][b] = (floatx4){0.f, 0.f, 0.f, 0.f};

  for (int k0 = 0; k0 < K; k0 += 32) {
    if (A_IS_F32) {
      const float* A = (const float*)Av;
      half8 h0, h1;
      if (k0 + sj < K) {
        const float* ap = A + (size_t)(bm + si) * K + k0 + sj;
        float4 v0 = *(const float4*)(ap + 0);
        float4 v1 = *(const float4*)(ap + 4);
        float4 v2 = *(const float4*)(ap + 8);
        float4 v3 = *(const float4*)(ap + 12);
        h0 = (half8){(_Float16)v0.x, (_Float16)v0.y, (_Float16)v0.z, (_Float16)v0.w,
                     (_Float16)v1.x, (_Float16)v1.y, (_Float16)v1.z, (_Float16)v1.w};
        h1 = (half8){(_Float16)v2.x, (_Float16)v2.y, (_Float16)v2.z, (_Float16)v2.w,
                     (_Float16)v3.x, (_Float16)v3.y, (_Float16)v3.z, (_Float16)v3.w};
      } else {
        h0 = (half8){0, 0, 0, 0, 0, 0, 0, 0};
        h1 = h0;
      }
      *(half8*)&As[si][sj] = h0;
      *(half8*)&As[si][sj + 8] = h1;
    } else {
      const __half* A = (const __half*)Av;
      uint4 u0, u1;
      if (k0 + sj < K) {
        const __half* ap = A + (size_t)(bm + si) * K + k0 + sj;
        u0 = *(const uint4*)ap;
        u1 = *(const uint4*)(ap + 8);
      } else {
        u0 = make_uint4(0, 0, 0, 0);
        u1 = u0;
      }
      *(uint4*)&As[si][sj] = u0;
      *(uint4*)&As[si][sj + 8] = u1;
    }
    {
      uint4 u0, u1;
      if (k0 + sj < K) {
        const _Float16* wp = Wt + (size_t)si * K + k0 + sj;
        u0 = *(const uint4*)wp;
        u1 = *(const uint4*)(wp + 8);
      } else {
        u0 = make_uint4(0, 0, 0, 0);
        u1 = u0;
      }
      *(uint4*)&Bs[si][sj] = u0;
      *(uint4*)&Bs[si][sj + 8] = u1;
    }
    __syncthreads();

    half8 a0 = *(const half8*)&As[w * 32 + rr][q * 8];
    half8 a1 = *(const half8*)&As[w * 32 + 16 + rr][q * 8];
#pragma unroll
    for (int nt = 0; nt < 8; ++nt) {
      half8 b = *(const half8*)&Bs[nt * 16 + rr][q * 8];
      acc[0][nt] = __builtin_amdgcn_mfma_f32_16x16x32_f16(a0, b, acc[0][nt], 0, 0, 0);
      acc[1][nt] = __builtin_amdgcn_mfma_f32_16x16x32_f16(a1, b, acc[1][nt], 0, 0, 0);
    }
    __syncthreads();
  }
#pragma unroll
  for (int mt = 0; mt < 2; ++mt)
#pragma unroll
    for (int nt = 0; nt < 8; ++nt)
#pragma unroll
      for (int r4 = 0; r4 < 4; ++r4) {
        int row = bm + w * 32 + mt * 16 + q * 4 + r4;
        C[(size_t)row * 128 + nt * 16 + rr] = __float2half(acc[mt][nt][r4]);
      }
}

// ---- CSR aggregation + bias + mish: one node per WAVE --------------------
// Scalar (wave-uniform) csr loads via readfirstlane; 32-bit gather offsets;
// unroll 16 for 16 outstanding gathers per wave.
__global__ __launch_bounds__(256) void k_agg(const __half2* __restrict__ h, const int* __restrict__ rowptr,
                                             const int2* __restrict__ csr, const float* __restrict__ dinv,
                                             const float* __restrict__ bias, __half2* __restrict__ out) {
  unsigned lane = threadIdx.x & 63u;
  int n = blockIdx.x * 4 + (threadIdx.x >> 6);
  float di = dinv[n];
  float2 self = __half22float2(h[((unsigned)n << 6) + lane]);
  float sx = 0.f, sy = 0.f;
  int p = __builtin_amdgcn_readfirstlane(rowptr[n]);
  int p1 = __builtin_amdgcn_readfirstlane(rowptr[n + 1]);
  for (; p + 16 <= p1; p += 16) {
    int2 c[16];
#pragma unroll
    for (int u = 0; u < 16; ++u) c[u] = csr[p + u];
    float2 f[16];
#pragma unroll
    for (int u = 0; u < 16; ++u) f[u] = __half22float2(h[((unsigned)c[u].x << 6) + lane]);
#pragma unroll
    for (int u = 0; u < 16; ++u) {
      float w = __int_as_float(c[u].y);
      sx += w * f[u].x;
      sy += w * f[u].y;
    }
  }
  for (; p + 4 <= p1; p += 4) {
    int2 c[4];
#pragma unroll
    for (int u = 0; u < 4; ++u) c[u] = csr[p + u];
    float2 f[4];
#pragma unroll
    for (int u = 0; u < 4; ++u) f[u] = __half22float2(h[((unsigned)c[u].x << 6) + lane]);
#pragma unroll
    for (int u = 0; u < 4; ++u) {
      float w = __int_as_float(c[u].y);
      sx += w * f[u].x;
      sy += w * f[u].y;
    }
  }
  for (; p < p1; ++p) {
    int2 c0 = csr[p];
    float2 f0 = __half22float2(h[((unsigned)c0.x << 6) + lane]);
    float w = __int_as_float(c0.y);
    sx += w * f0.x;
    sy += w * f0.y;
  }
  float ax = di * (di * self.x + sx);
  float ay = di * (di * self.y + sy);
  float2 bb = ((const float2*)bias)[lane];
  out[((unsigned)n << 6) + lane] = __floats2half2_rn(mish_f(ax + bb.x), mish_f(ay + bb.y));
}

// ---- readout (fp16 h): o8[n,k] = mish(h[n,:]@ro_w[:,k] + ro_b[k]) --------
__global__ __launch_bounds__(256) void k_ro(const __half2* __restrict__ h, const float* __restrict__ rw,
                                            const float* __restrict__ rb, float* __restrict__ o8) {
  __shared__ float w[128 * 8];
  int t = threadIdx.x;
  for (int i = t; i < 1024; i += 256) w[i] = rw[i];
  __syncthreads();
  int n = blockIdx.x * 32 + (t >> 3);
  int k = t & 7;
  const __half2* hr = h + (size_t)n * 64;
  float acc = rb[k];
#pragma unroll 4
  for (int j = 0; j < 64; ++j) {
    float2 hv = __half22float2(hr[j]);
    acc += hv.x * w[(2 * j) * 8 + k] + hv.y * w[(2 * j + 1) * 8 + k];
  }
  o8[(size_t)n * 8 + k] = mish_f(acc);
}

// ---- fc1 split-K: z += feats[g, kc:kc+128] @ w[kc:kc+128, :] -------------
__global__ void k_fc1_init(const float* __restrict__ b, float* __restrict__ z) {
  int i = blockIdx.x * blockDim.x + threadIdx.x;
  if (i < 128 * 400) z[i] = b[i % 400];
}

__global__ __launch_bounds__(448) void k_fc1(const float* __restrict__ feats, const float* __restrict__ w,
                                             float* __restrict__ z) {
  __shared__ float fs[8][128];
  int t = threadIdx.x;
  int kc = blockIdx.x * 128;
  int g0 = blockIdx.y * 8;
  for (int i = t; i < 1024; i += 448) {
    int g = i >> 7, k = i & 127;
    fs[g][k] = feats[(size_t)(g0 + g) * 3200 + kc + k];
  }
  __syncthreads();
  if (t < 400) {
    float a[8];
#pragma unroll
    for (int g = 0; g < 8; ++g) a[g] = 0.0f;
    for (int k = 0; k < 128; ++k) {
      float wv = w[(size_t)(kc + k) * 400 + t];
#pragma unroll
      for (int g = 0; g < 8; ++g) a[g] += fs[g][k] * wv;
    }
#pragma unroll
    for (int g = 0; g < 8; ++g) atomicAdd(&z[(size_t)(g0 + g) * 400 + t], a[g]);
  }
}

// ---- batchnorm stats: one block per feature, thread = batch element ------
__global__ __launch_bounds__(128) void k_bn(const float* __restrict__ z, const float* __restrict__ gamma,
                                            const float* __restrict__ beta, float* __restrict__ gs,
                                            float* __restrict__ gb) {
  int j = blockIdx.x;
  int b = threadIdx.x;
  float v = z[b * 400 + j];
  float s = v, s2 = v * v;
#pragma unroll
  for (int off = 1; off < 64; off <<= 1) {
    s += __shfl_xor(s, off);
    s2 += __shfl_xor(s2, off);
  }
  __shared__ float ls[2], ls2[2];
  if ((b & 63) == 0) {
    ls[b >> 6] = s;
    ls2[b >> 6] = s2;
  }
  __syncthreads();
  if (b == 0) {
    float mu = (ls[0] + ls[1]) * (1.0f / 128.0f);
    float var = (ls2[0] + ls2[1]) * (1.0f / 128.0f) - mu * mu;
    float rs = rsqrtf(var + 1e-5f);
    float g = gamma[j] * rs;
    gs[j] = g;
    gb[j] = beta[j] - mu * g;
  }
}

// ---- fc2: one block per graph, block-reduce over j -----------------------
__global__ __launch_bounds__(256) void k_fc2(const float* __restrict__ z, const float* __restrict__ gs,
                                             const float* __restrict__ gb, const float* __restrict__ w2,
                                             const float* __restrict__ b2, float* __restrict__ out) {
  int bg = blockIdx.x;
  int t = threadIdx.x;
  float a0 = 0.f, a1 = 0.f;
  for (int j = t; j < 400; j += 256) {
    float zn = z[bg * 400 + j] * gs[j] + gb[j];
    float m = mish_f(zn);
    a0 += m * w2[j * 2];
    a1 += m * w2[j * 2 + 1];
  }
#pragma unroll
  for (int off = 1; off < 64; off <<= 1) {
    a0 += __shfl_xor(a0, off);
    a1 += __shfl_xor(a1, off);
  }
  __shared__ float s0[4], s1[4];
  if ((t & 63) == 0) {
    s0[t >> 6] = a0;
    s1[t >> 6] = a1;
  }
  __syncthreads();
  if (t == 0) {
    out[bg * 2 + 0] = b2[0] + s0[0] + s0[1] + s0[2] + s0[3];
    out[bg * 2 + 1] = b2[1] + s1[0] + s1[1] + s1[2] + s1[3];
  }
}

extern "C" void kernel_launch(void* const* d_in, const int* in_sizes, int n_in,
                              void* d_out, int out_size, void* d_ws, size_t ws_size,
                              hipStream_t stream) {
  (void)in_sizes; (void)n_in; (void)out_size; (void)ws_size;
  const float* x   = (const float*)d_in[0];
  const int*   ei  = (const int*)d_in[1];
  const float* ew  = (const float*)d_in[2];
  const float* c1w = (const float*)d_in[4];
  const float* c1b = (const float*)d_in[5];
  const float* c2w = (const float*)d_in[6];
  const float* c2b = (const float*)d_in[7];
  const float* rw  = (const float*)d_in[8];
  const float* rb  = (const float*)d_in[9];
  const float* f1w = (const float*)d_in[10];
  const float* f1b = (const float*)d_in[11];
  const float* bng = (const float*)d_in[12];
  const float* bnb = (const float*)d_in[13];
  const float* f2w = (const float*)d_in[14];
  const float* f2b = (const float*)d_in[15];
  float* out = (float*)d_out;

  char* ws = (char*)d_ws;
  size_t off = 0;
  auto alloc = [&](size_t bytes) {
    void* p = ws + off;
    off = (off + bytes + 255) & ~(size_t)255;
    return p;
  };
  float* dinv    = (float*)alloc((size_t)NN * 4);
  int*   cnt     = (int*)alloc((size_t)NN * 4);
  int*   rowptr  = (int*)alloc((size_t)(NN + 1) * 4);
  int*   bsum    = (int*)alloc(200 * 4);
  int*   boff    = (int*)alloc(200 * 4);
  unsigned* G    = (unsigned*)alloc((size_t)NBKT * NB * 4);  // 800 KB
  unsigned* btot = (unsigned*)alloc(NBKT * 4);
  unsigned* bbase= (unsigned*)alloc((NBKT + 1) * 4);
  int2*  csr     = (int2*)alloc((size_t)NE * 8);             // 16.4 MB
  __half* A1     = (__half*)alloc((size_t)NN * F * 2);       // gemm out (fp16)
  __half* B1     = (__half*)alloc((size_t)NN * F * 2);       // agg out (fp16)
  _Float16* Wt1  = (_Float16*)alloc((size_t)400 * 128 * 2);
  _Float16* Wt2  = (_Float16*)alloc((size_t)128 * 128 * 2);
  float* o8      = (float*)alloc((size_t)NN * 8 * 4);
  float* z       = (float*)alloc((size_t)128 * 400 * 4);
  float* gs      = (float*)alloc(400 * 4);
  float* gb      = (float*)alloc(400 * 4);

  // E (16 MB) aliases A1+B1 (26 MB): E's last reader (k_fscat) completes
  // before gemm1 writes A1 (stream-ordered).
  uint2* E = (uint2*)A1;

  k_chist<<<NB, 256, 0, stream>>>(ei, G);
  k_bscan<<<NBKT, 64, 0, stream>>>(G, btot);
  k_bbase<<<1, 256, 0, stream>>>(btot, bbase);
  k_cscat<<<NB, 256, 0, stream>>>(ei, ew, G, bbase, E);
  k_fcnt<<<NBKT, 256, 0, stream>>>(E, bbase, cnt, dinv);
  k_scan1<<<NN / 256, 256, 0, stream>>>(cnt, bsum);
  k_scan2<<<1, 256, 0, stream>>>(bsum, boff, rowptr);
  k_scan3<<<NN / 256, 256, 0, stream>>>(cnt, boff, rowptr);
  k_fscat<<<NBKT, 256, 0, stream>>>(E, bbase, rowptr, dinv, csr);

  k_prep_w<<<(400 * 128 + 255) / 256, 256, 0, stream>>>(c1w, Wt1, 400);
  k_prep_w<<<(128 * 128 + 255) / 256, 256, 0, stream>>>(c2w, Wt2, 128);

  // conv1: h = x@W1 (MFMA, fp16 out) ; agg+bias+mish (fp16 out)
  k_gemm16<true><<<NN / 128, 256, 0, stream>>>(x, Wt1, A1, 400);
  k_agg<<<NN / 4, 256, 0, stream>>>((const __half2*)A1, rowptr, csr, dinv, c1b, (__half2*)B1);
  // conv2
  k_gemm16<false><<<NN / 128, 256, 0, stream>>>(B1, Wt2, A1, 128);
  k_agg<<<NN / 4, 256, 0, stream>>>((const __half2*)A1, rowptr, csr, dinv, c2b, (__half2*)B1);
  // readout -> feats (o8 flat IS feats[128][3200])
  k_ro<<<NN / 32, 256, 0, stream>>>((const __half2*)B1, rw, rb, o8);
  k_fc1_init<<<(128 * 400 + 255) / 256, 256, 0, stream>>>(f1b, z);
  {
    dim3 g(25, 16);
    k_fc1<<<g, 448, 0, stream>>>(o8, f1w, z);
  }
  k_bn<<<400, 128, 0, stream>>>(z, bng, bnb, gs, gb);
  k_fc2<<<128, 256, 0, stream>>>(z, gs, gb, f2w, f2b, out);
}